// Round 1
// baseline (956.007 us; speedup 1.0000x reference)
//
#include <hip/hip_runtime.h>
#include <math.h>

#define NODES 100000
#define EDGES 1250000
#define HD 64
#define NFD 16
#define CHUNK 1024
#define NCHUNK ((NODES + CHUNK - 1) / CHUNK)

// ---------------- graph build ----------------

__global__ void k_zero(int* __restrict__ p, int n) {
  int i = blockIdx.x * blockDim.x + threadIdx.x;
  if (i < n) p[i] = 0;
}

__global__ void k_hist(const int* __restrict__ ei, int* __restrict__ deg) {
  int e = blockIdx.x * blockDim.x + threadIdx.x;
  if (e < EDGES) atomicAdd(&deg[ei[EDGES + e]], 1);
}

__global__ void k_scan1(const int* __restrict__ deg, int* __restrict__ part) {
  __shared__ int lds[256];
  int t = threadIdx.x, b = blockIdx.x;
  int base = b * CHUNK + t * 4;
  int s = 0;
#pragma unroll
  for (int m = 0; m < 4; m++) { int i = base + m; if (i < NODES) s += deg[i]; }
  lds[t] = s; __syncthreads();
  for (int off = 128; off > 0; off >>= 1) {
    if (t < off) lds[t] += lds[t + off];
    __syncthreads();
  }
  if (t == 0) part[b] = lds[0];
}

__global__ void k_scan2(int* __restrict__ part) {
  if (threadIdx.x == 0 && blockIdx.x == 0) {
    int run = 0;
    for (int c = 0; c < NCHUNK; c++) { int v = part[c]; part[c] = run; run += v; }
  }
}

__global__ void k_scan3(const int* __restrict__ deg, const int* __restrict__ part,
                        int* __restrict__ rowptr, int* __restrict__ cur,
                        float* __restrict__ dis) {
  __shared__ int lds[256];
  int t = threadIdx.x, b = blockIdx.x;
  int base = b * CHUNK + t * 4;
  int dl[4]; int s = 0;
#pragma unroll
  for (int m = 0; m < 4; m++) { int i = base + m; dl[m] = (i < NODES) ? deg[i] : 0; s += dl[m]; }
  lds[t] = s; __syncthreads();
  for (int off = 1; off < 256; off <<= 1) {
    int add = (t >= off) ? lds[t - off] : 0;
    __syncthreads();
    lds[t] += add;
    __syncthreads();
  }
  int run = part[b] + lds[t] - s;  // exclusive prefix for this thread
#pragma unroll
  for (int m = 0; m < 4; m++) {
    int i = base + m;
    if (i < NODES) {
      rowptr[i] = run; cur[i] = run;
      dis[i] = 1.0f / sqrtf((float)(dl[m] + 1));  // GCN: indeg + self-loop
    }
    run += dl[m];
  }
  if (b == 0 && t == 0) rowptr[NODES] = EDGES;
}

__global__ void k_fill(const int* __restrict__ ei, const float* __restrict__ ea,
                       int* __restrict__ cur, float4* __restrict__ edat) {
  int e = blockIdx.x * blockDim.x + threadIdx.x;
  if (e >= EDGES) return;
  int s = ei[e], d = ei[EDGES + e];
  int p = atomicAdd(&cur[d], 1);
  float4 v;
  v.x = __int_as_float(s);
  v.y = ea[e * 3 + 0]; v.z = ea[e * 3 + 1]; v.w = ea[e * 3 + 2];
  edat[p] = v;
}

// ---------------- fused node GEMMs ----------------

// h = x@Wn + bn -> hA ; h0 = h@Wl + bl -> hB ; cvec = h0 . Wa[0:64] ; dvec = h0 . Wa[64:128]
__global__ __launch_bounds__(256) void k_node_lin0(
    const float* __restrict__ x,
    const float* __restrict__ Wn, const float* __restrict__ bn,
    const float* __restrict__ Wl, const float* __restrict__ bl,
    const float* __restrict__ Wa,
    float* __restrict__ hA, float* __restrict__ hB,
    float* __restrict__ cvec, float* __restrict__ dvec) {
  __shared__ float sWn[NFD * HD];
  __shared__ float sWl[HD * HD];
  __shared__ float sbn[HD], sbl[HD], sWa[128];
  for (int i = threadIdx.x; i < NFD * HD; i += 256) sWn[i] = Wn[i];
  for (int i = threadIdx.x; i < HD * HD; i += 256) sWl[i] = Wl[i];
  if (threadIdx.x < HD) { sbn[threadIdx.x] = bn[threadIdx.x]; sbl[threadIdx.x] = bl[threadIdx.x]; }
  if (threadIdx.x < 128) sWa[threadIdx.x] = Wa[threadIdx.x];
  __syncthreads();
  int wid = threadIdx.x >> 6, lane = threadIdx.x & 63;
  for (int node = blockIdx.x * 4 + wid; node < NODES; node += gridDim.x * 4) {
    float xv = (lane < NFD) ? x[node * NFD + lane] : 0.f;
    float h = sbn[lane];
#pragma unroll
    for (int k = 0; k < NFD; k++) h = fmaf(__shfl(xv, k), sWn[k * HD + lane], h);
    hA[node * HD + lane] = h;
    float h0 = sbl[lane];
#pragma unroll
    for (int k = 0; k < HD; k++) h0 = fmaf(__shfl(h, k), sWl[k * HD + lane], h0);
    hB[node * HD + lane] = h0;
    float c = h0 * sWa[lane];
    float d = h0 * sWa[64 + lane];
#pragma unroll
    for (int off = 32; off > 0; off >>= 1) { c += __shfl_xor(c, off); d += __shfl_xor(d, off); }
    if (lane == 0) { cvec[node] = c; dvec[node] = d; }
  }
}

// ---------------- layer 0: edge attention aggregation ----------------

__global__ __launch_bounds__(256) void k_agg_att(
    const float4* __restrict__ edat, const int* __restrict__ rowptr,
    const float* __restrict__ hA, const float* __restrict__ hB,
    const float* __restrict__ cvec, const float* __restrict__ dvec,
    const float* __restrict__ Wa, const float* __restrict__ ba,
    const float* __restrict__ gamma, const float* __restrict__ beta,
    float* __restrict__ hC) {
  int wid = threadIdx.x >> 6, lane = threadIdx.x & 63;
  int node = blockIdx.x * 4 + wid;
  if (node >= NODES) return;
  float wa0 = Wa[128], wa1 = Wa[129], wa2 = Wa[130], bb = ba[0];
  int start = rowptr[node], end = rowptr[node + 1];
  float ci = cvec[node];
  float acc = 0.f;
  for (int base = start; base < end; base += 64) {
    int idx = base + lane;
    bool valid = idx < end;
    float4 ed = valid ? edat[idx] : make_float4(0.f, 0.f, 0.f, 0.f);
    int sl = __float_as_int(ed.x);
    float dv = valid ? dvec[sl] : 0.f;
    float alin = ci + dv + ed.y * wa0 + ed.z * wa1 + ed.w * wa2 + bb;
    float lr = alin >= 0.f ? alin : 0.01f * alin;
    float a = 1.f / (1.f + expf(-lr));
    int cnt = min(end - base, 64);
    for (int m = 0; m < cnt; m++) {
      int s = __shfl(sl, m);
      float am = __shfl(a, m);
      acc = fmaf(am, hB[s * HD + lane], acc);
    }
  }
  float inv = 1.0f / sqrtf(1.f + 1e-5f);
  float v = acc * (gamma[lane] * inv) + beta[lane];
  v = fmaxf(v, 0.f) + hA[node * HD + lane];
  hC[node * HD + lane] = v;
}

// ---------------- layer 1: SAGE ----------------

__global__ __launch_bounds__(256) void k_agg_mean(
    const float4* __restrict__ edat, const int* __restrict__ rowptr,
    const float* __restrict__ hC, float* __restrict__ hB) {
  int wid = threadIdx.x >> 6, lane = threadIdx.x & 63;
  int node = blockIdx.x * 4 + wid;
  if (node >= NODES) return;
  int start = rowptr[node], end = rowptr[node + 1];
  float acc = 0.f;
  for (int base = start; base < end; base += 64) {
    int idx = base + lane;
    bool valid = idx < end;
    float fx = valid ? edat[idx].x : 0.f;
    int sl = __float_as_int(fx);
    int cnt = min(end - base, 64);
    for (int m = 0; m < cnt; m++) {
      int s = __shfl(sl, m);
      acc += hC[s * HD + lane];
    }
  }
  float degf = (float)(end - start);
  hB[node * HD + lane] = acc / fmaxf(degf, 1.f);
}

__global__ __launch_bounds__(256) void k_sage(
    const float* __restrict__ hB, const float* __restrict__ hC,
    const float* __restrict__ Wl, const float* __restrict__ bl,
    const float* __restrict__ Wr,
    const float* __restrict__ gamma, const float* __restrict__ beta,
    float* __restrict__ hA) {
  __shared__ float sWl[HD * HD], sWr[HD * HD], sbl[HD], sg[HD], sb[HD];
  float inv = 1.0f / sqrtf(1.f + 1e-5f);
  for (int i = threadIdx.x; i < HD * HD; i += 256) { sWl[i] = Wl[i]; sWr[i] = Wr[i]; }
  if (threadIdx.x < HD) {
    sbl[threadIdx.x] = bl[threadIdx.x];
    sg[threadIdx.x] = gamma[threadIdx.x] * inv;
    sb[threadIdx.x] = beta[threadIdx.x];
  }
  __syncthreads();
  int wid = threadIdx.x >> 6, lane = threadIdx.x & 63;
  for (int node = blockIdx.x * 4 + wid; node < NODES; node += gridDim.x * 4) {
    float rB = hB[node * HD + lane];
    float rC = hC[node * HD + lane];
    float acc = sbl[lane];
#pragma unroll
    for (int k = 0; k < HD; k++) acc = fmaf(__shfl(rB, k), sWl[k * HD + lane], acc);
#pragma unroll
    for (int k = 0; k < HD; k++) acc = fmaf(__shfl(rC, k), sWr[k * HD + lane], acc);
    float v = acc * sg[lane] + sb[lane];
    v = fmaxf(v, 0.f) + rC;
    hA[node * HD + lane] = v;
  }
}

// ---------------- layer 2: GCN ----------------

__global__ __launch_bounds__(256) void k_gcnmm(
    const float* __restrict__ hA, const float* __restrict__ Wg, float* __restrict__ hB) {
  __shared__ float sW[HD * HD];
  for (int i = threadIdx.x; i < HD * HD; i += 256) sW[i] = Wg[i];
  __syncthreads();
  int wid = threadIdx.x >> 6, lane = threadIdx.x & 63;
  for (int node = blockIdx.x * 4 + wid; node < NODES; node += gridDim.x * 4) {
    float r = hA[node * HD + lane];
    float acc = 0.f;
#pragma unroll
    for (int k = 0; k < HD; k++) acc = fmaf(__shfl(r, k), sW[k * HD + lane], acc);
    hB[node * HD + lane] = acc;
  }
}

__global__ __launch_bounds__(256) void k_agg_gcn(
    const float4* __restrict__ edat, const int* __restrict__ rowptr,
    const float* __restrict__ dis,
    const float* __restrict__ hA, const float* __restrict__ hB,
    const float* __restrict__ bg,
    const float* __restrict__ gamma, const float* __restrict__ beta,
    float* __restrict__ hC) {
  int wid = threadIdx.x >> 6, lane = threadIdx.x & 63;
  int node = blockIdx.x * 4 + wid;
  if (node >= NODES) return;
  int start = rowptr[node], end = rowptr[node + 1];
  float di = dis[node];
  float acc = di * hB[node * HD + lane];  // self-loop term (before outer di scale)
  for (int base = start; base < end; base += 64) {
    int idx = base + lane;
    bool valid = idx < end;
    float fx = valid ? edat[idx].x : 0.f;
    int sl = __float_as_int(fx);
    float dsl = valid ? dis[sl] : 0.f;
    int cnt = min(end - base, 64);
    for (int m = 0; m < cnt; m++) {
      int s = __shfl(sl, m);
      float dsm = __shfl(dsl, m);
      acc = fmaf(dsm, hB[s * HD + lane], acc);
    }
  }
  float inv = 1.0f / sqrtf(1.f + 1e-5f);
  float v = di * acc + bg[lane];
  v = v * (gamma[lane] * inv) + beta[lane];
  v = fmaxf(v, 0.f) + hA[node * HD + lane];
  hC[node * HD + lane] = v;
}

// ---------------- regressor head ----------------

__global__ __launch_bounds__(256) void k_reg(
    const float* __restrict__ hC,
    const float* __restrict__ W1, const float* __restrict__ b1,
    const float* __restrict__ W2, const float* __restrict__ b2,
    const float* __restrict__ W3, const float* __restrict__ b3,
    float* __restrict__ out) {
  __shared__ float sW1[HD * HD], sW2[HD * 32], sb1[HD], sb2[32], sW3[32];
  for (int i = threadIdx.x; i < HD * HD; i += 256) sW1[i] = W1[i];
  for (int i = threadIdx.x; i < HD * 32; i += 256) sW2[i] = W2[i];
  if (threadIdx.x < HD) sb1[threadIdx.x] = b1[threadIdx.x];
  if (threadIdx.x < 32) { sb2[threadIdx.x] = b2[threadIdx.x]; sW3[threadIdx.x] = W3[threadIdx.x]; }
  __syncthreads();
  float bb3 = b3[0];
  int wid = threadIdx.x >> 6, lane = threadIdx.x & 63;
  for (int node = blockIdx.x * 4 + wid; node < NODES; node += gridDim.x * 4) {
    float r = hC[node * HD + lane];
    float t1 = sb1[lane];
#pragma unroll
    for (int k = 0; k < HD; k++) t1 = fmaf(__shfl(r, k), sW1[k * HD + lane], t1);
    t1 = fmaxf(t1, 0.f);
    float t2 = (lane < 32) ? sb2[lane] : 0.f;
#pragma unroll
    for (int k = 0; k < HD; k++) t2 = fmaf(__shfl(t1, k), sW2[k * 32 + (lane & 31)], t2);
    t2 = fmaxf(t2, 0.f);
    float contrib = (lane < 32) ? t2 * sW3[lane] : 0.f;
#pragma unroll
    for (int off = 32; off > 0; off >>= 1) contrib += __shfl_xor(contrib, off);
    if (lane == 0) out[node] = contrib + bb3;
  }
}

// ---------------- host launch ----------------

extern "C" void kernel_launch(void* const* d_in, const int* in_sizes, int n_in,
                              void* d_out, int out_size, void* d_ws, size_t ws_size,
                              hipStream_t stream) {
  const float* x      = (const float*)d_in[0];
  const float* ea     = (const float*)d_in[1];
  const int*   ei     = (const int*)d_in[2];
  const float* W_node = (const float*)d_in[3];
  const float* b_node = (const float*)d_in[4];
  // d_in[5], d_in[6]: W_edge/b_edge — unused by the reference output
  const float* W_lin0 = (const float*)d_in[7];
  const float* b_lin0 = (const float*)d_in[8];
  const float* W_att0 = (const float*)d_in[9];
  const float* b_att0 = (const float*)d_in[10];
  const float* W_sl   = (const float*)d_in[11];
  const float* b_sl   = (const float*)d_in[12];
  const float* W_sr   = (const float*)d_in[13];
  const float* W_gcn  = (const float*)d_in[14];
  const float* b_gcn  = (const float*)d_in[15];
  const float* bn_g   = (const float*)d_in[16];  // [3,64]
  const float* bn_b   = (const float*)d_in[17];
  const float* W_r1   = (const float*)d_in[18];
  const float* b_r1   = (const float*)d_in[19];
  const float* W_r2   = (const float*)d_in[20];
  const float* b_r2   = (const float*)d_in[21];
  const float* W_r3   = (const float*)d_in[22];
  const float* b_r3   = (const float*)d_in[23];
  float* out = (float*)d_out;

  char* ws = (char*)d_ws;
  size_t o = 0;
  auto alloc = [&](size_t bytes) -> void* {
    void* p = ws + o;
    o += (bytes + 255) & ~(size_t)255;
    return p;
  };
  int*    deg    = (int*)alloc(NODES * 4);
  int*    rowptr = (int*)alloc((NODES + 1) * 4);
  int*    cur    = (int*)alloc(NODES * 4);
  int*    part   = (int*)alloc(256 * 4);
  float4* edat   = (float4*)alloc((size_t)EDGES * 16);
  float*  hA     = (float*)alloc((size_t)NODES * HD * 4);
  float*  hB     = (float*)alloc((size_t)NODES * HD * 4);
  float*  hC     = (float*)alloc((size_t)NODES * HD * 4);
  float*  cvec   = (float*)alloc(NODES * 4);
  float*  dvec   = (float*)alloc(NODES * 4);
  float*  dis    = (float*)alloc(NODES * 4);
  (void)ws_size; (void)in_sizes; (void)n_in; (void)out_size;

  const int EB = (EDGES + 255) / 256;
  const int NBW = (NODES + 3) / 4;  // wave-per-node blocks (4 waves/block)

  k_zero<<<(NODES + 255) / 256, 256, 0, stream>>>(deg, NODES);
  k_hist<<<EB, 256, 0, stream>>>(ei, deg);
  k_scan1<<<NCHUNK, 256, 0, stream>>>(deg, part);
  k_scan2<<<1, 64, 0, stream>>>(part);
  k_scan3<<<NCHUNK, 256, 0, stream>>>(deg, part, rowptr, cur, dis);
  k_fill<<<EB, 256, 0, stream>>>(ei, ea, cur, edat);

  k_node_lin0<<<2048, 256, 0, stream>>>(x, W_node, b_node, W_lin0, b_lin0, W_att0,
                                        hA, hB, cvec, dvec);
  k_agg_att<<<NBW, 256, 0, stream>>>(edat, rowptr, hA, hB, cvec, dvec,
                                     W_att0, b_att0, bn_g + 0 * HD, bn_b + 0 * HD, hC);
  k_agg_mean<<<NBW, 256, 0, stream>>>(edat, rowptr, hC, hB);
  k_sage<<<2048, 256, 0, stream>>>(hB, hC, W_sl, b_sl, W_sr,
                                   bn_g + 1 * HD, bn_b + 1 * HD, hA);
  k_gcnmm<<<2048, 256, 0, stream>>>(hA, W_gcn, hB);
  k_agg_gcn<<<NBW, 256, 0, stream>>>(edat, rowptr, dis, hA, hB, b_gcn,
                                     bn_g + 2 * HD, bn_b + 2 * HD, hC);
  k_reg<<<2048, 256, 0, stream>>>(hC, W_r1, b_r1, W_r2, b_r2, W_r3, b_r3, out);
}

// Round 2
// 489.470 us; speedup vs baseline: 1.9531x; 1.9531x over previous
//
#include <hip/hip_runtime.h>
#include <math.h>

#define NODES 100000
#define EDGES 1250000
#define HD 64
#define NFD 16
#define CHUNK 1024
#define NCHUNK ((NODES + CHUNK - 1) / CHUNK)
#define BN_INV 0.9999950000374996f  // 1/sqrt(1+1e-5)

#define LOAD16(dst, ptr)                                   \
  {                                                        \
    const float4* _p = (const float4*)(ptr);               \
    float4 _a = _p[0], _b = _p[1], _c = _p[2], _d = _p[3]; \
    dst[0] = _a.x; dst[1] = _a.y; dst[2] = _a.z; dst[3] = _a.w;    \
    dst[4] = _b.x; dst[5] = _b.y; dst[6] = _b.z; dst[7] = _b.w;    \
    dst[8] = _c.x; dst[9] = _c.y; dst[10] = _c.z; dst[11] = _c.w;  \
    dst[12] = _d.x; dst[13] = _d.y; dst[14] = _d.z; dst[15] = _d.w; \
  }

#define STORE16(ptr, src)                                       \
  {                                                             \
    float4* _p = (float4*)(ptr);                                \
    _p[0] = make_float4(src[0], src[1], src[2], src[3]);        \
    _p[1] = make_float4(src[4], src[5], src[6], src[7]);        \
    _p[2] = make_float4(src[8], src[9], src[10], src[11]);      \
    _p[3] = make_float4(src[12], src[13], src[14], src[15]);    \
  }

// ---------------- graph build ----------------

__global__ void k_zero(int* __restrict__ p, int n) {
  int i = blockIdx.x * blockDim.x + threadIdx.x;
  if (i < n) p[i] = 0;
}

__global__ void k_hist(const int* __restrict__ ei, int* __restrict__ deg) {
  int e = blockIdx.x * blockDim.x + threadIdx.x;
  if (e < EDGES) atomicAdd(&deg[ei[EDGES + e]], 1);
}

__global__ void k_scan1(const int* __restrict__ deg, int* __restrict__ part) {
  __shared__ int lds[256];
  int t = threadIdx.x, b = blockIdx.x;
  int base = b * CHUNK + t * 4;
  int s = 0;
#pragma unroll
  for (int m = 0; m < 4; m++) { int i = base + m; if (i < NODES) s += deg[i]; }
  lds[t] = s; __syncthreads();
  for (int off = 128; off > 0; off >>= 1) {
    if (t < off) lds[t] += lds[t + off];
    __syncthreads();
  }
  if (t == 0) part[b] = lds[0];
}

__global__ void k_scan2(int* __restrict__ part) {
  if (threadIdx.x == 0 && blockIdx.x == 0) {
    int run = 0;
    for (int c = 0; c < NCHUNK; c++) { int v = part[c]; part[c] = run; run += v; }
  }
}

__global__ void k_scan3(const int* __restrict__ deg, const int* __restrict__ part,
                        int* __restrict__ rowptr, int* __restrict__ cur,
                        float* __restrict__ dis) {
  __shared__ int lds[256];
  int t = threadIdx.x, b = blockIdx.x;
  int base = b * CHUNK + t * 4;
  int dl[4]; int s = 0;
#pragma unroll
  for (int m = 0; m < 4; m++) { int i = base + m; dl[m] = (i < NODES) ? deg[i] : 0; s += dl[m]; }
  lds[t] = s; __syncthreads();
  for (int off = 1; off < 256; off <<= 1) {
    int add = (t >= off) ? lds[t - off] : 0;
    __syncthreads();
    lds[t] += add;
    __syncthreads();
  }
  int run = part[b] + lds[t] - s;  // exclusive prefix for this thread
#pragma unroll
  for (int m = 0; m < 4; m++) {
    int i = base + m;
    if (i < NODES) {
      rowptr[i] = run; cur[i] = run;
      dis[i] = 1.0f / sqrtf((float)(dl[m] + 1));  // GCN: indeg + self-loop
    }
    run += dl[m];
  }
  if (b == 0 && t == 0) rowptr[NODES] = EDGES;
}

__global__ void k_fill(const int* __restrict__ ei, const float* __restrict__ ea,
                       int* __restrict__ cur, int* __restrict__ esrc,
                       float4* __restrict__ edat) {
  int e = blockIdx.x * blockDim.x + threadIdx.x;
  if (e >= EDGES) return;
  int s = ei[e], d = ei[EDGES + e];
  int p = atomicAdd(&cur[d], 1);
  esrc[p] = s;
  edat[p] = make_float4(__int_as_float(d), ea[e * 3 + 0], ea[e * 3 + 1], ea[e * 3 + 2]);
}

// edge-parallel attention coefficients: sa[p] = (srcbits, a)
__global__ void k_att(const int* __restrict__ esrc, const float4* __restrict__ edat,
                      const float* __restrict__ cvec, const float* __restrict__ dvec,
                      const float* __restrict__ Wa, const float* __restrict__ ba,
                      float2* __restrict__ sa) {
  int e = blockIdx.x * blockDim.x + threadIdx.x;
  if (e >= EDGES) return;
  float4 ed = edat[e];
  int d = __float_as_int(ed.x);
  int s = esrc[e];
  float alin = cvec[d] + dvec[s] + ed.y * Wa[128] + ed.z * Wa[129] + ed.w * Wa[130] + ba[0];
  float lr = alin >= 0.f ? alin : 0.01f * alin;
  float a = 1.f / (1.f + expf(-lr));
  sa[e] = make_float2(__int_as_float(s), a);
}

// ---------------- row-per-thread node GEMMs ----------------

// h = x@Wn + bn -> hA ; h0 = h@Wl + bl -> hB ; cvec = h0.Wa[0:64] ; dvec = h0.Wa[64:128]
__global__ __launch_bounds__(256) void k_lin0(
    const float* __restrict__ x,
    const float* __restrict__ Wn, const float* __restrict__ bn,
    const float* __restrict__ Wl, const float* __restrict__ bl,
    const float* __restrict__ Wa,
    float* __restrict__ hA, float* __restrict__ hB,
    float* __restrict__ cvec, float* __restrict__ dvec) {
  int n = blockIdx.x * 256 + threadIdx.x;
  if (n >= NODES) return;
  float xv[16];
  LOAD16(xv, x + (size_t)n * NFD);
  // stage 1: h = x@Wn + bn
  for (int cc = 0; cc < 4; cc++) {
    int c0 = cc * 16;
    float acc[16];
#pragma unroll
    for (int j = 0; j < 16; j++) acc[j] = bn[c0 + j];
#pragma unroll
    for (int k = 0; k < 16; k++)
#pragma unroll
      for (int j = 0; j < 16; j++)
        acc[j] = fmaf(xv[k], Wn[k * HD + c0 + j], acc[j]);
    STORE16(hA + (size_t)n * HD + c0, acc);
  }
  // stage 2: h0 = h@Wl + bl (+ attention dot precompute)
  const float* hrow = hA + (size_t)n * HD;
  float cn = 0.f, dn = 0.f;
  for (int cc = 0; cc < 4; cc++) {
    int c0 = cc * 16;
    float acc[16];
#pragma unroll
    for (int j = 0; j < 16; j++) acc[j] = bl[c0 + j];
    for (int kc = 0; kc < 4; kc++) {
      float av[16];
      LOAD16(av, hrow + kc * 16);
#pragma unroll
      for (int kk = 0; kk < 16; kk++)
#pragma unroll
        for (int j = 0; j < 16; j++)
          acc[j] = fmaf(av[kk], Wl[(kc * 16 + kk) * HD + c0 + j], acc[j]);
    }
#pragma unroll
    for (int j = 0; j < 16; j++) {
      cn = fmaf(acc[j], Wa[c0 + j], cn);
      dn = fmaf(acc[j], Wa[64 + c0 + j], dn);
    }
    STORE16(hB + (size_t)n * HD + c0, acc);
  }
  cvec[n] = cn;
  dvec[n] = dn;
}

// sage: hA = relu(BN1(mean@Wl + bl + hC@Wr)) + hC
__global__ __launch_bounds__(256) void k_sage(
    const float* __restrict__ hM, const float* __restrict__ hC,
    const float* __restrict__ Wl, const float* __restrict__ bl,
    const float* __restrict__ Wr,
    const float* __restrict__ g, const float* __restrict__ bt,
    float* __restrict__ hA) {
  int n = blockIdx.x * 256 + threadIdx.x;
  if (n >= NODES) return;
  const float* mrow = hM + (size_t)n * HD;
  const float* crow = hC + (size_t)n * HD;
  for (int cc = 0; cc < 4; cc++) {
    int c0 = cc * 16;
    float acc[16];
#pragma unroll
    for (int j = 0; j < 16; j++) acc[j] = bl[c0 + j];
    for (int kc = 0; kc < 4; kc++) {
      float av[16], bv[16];
      LOAD16(av, mrow + kc * 16);
      LOAD16(bv, crow + kc * 16);
#pragma unroll
      for (int kk = 0; kk < 16; kk++)
#pragma unroll
        for (int j = 0; j < 16; j++)
          acc[j] = fmaf(av[kk], Wl[(kc * 16 + kk) * HD + c0 + j], acc[j]);
#pragma unroll
      for (int kk = 0; kk < 16; kk++)
#pragma unroll
        for (int j = 0; j < 16; j++)
          acc[j] = fmaf(bv[kk], Wr[(kc * 16 + kk) * HD + c0 + j], acc[j]);
    }
    float rv[16];
    LOAD16(rv, crow + c0);
#pragma unroll
    for (int j = 0; j < 16; j++)
      acc[j] = fmaxf(acc[j] * (g[c0 + j] * BN_INV) + bt[c0 + j], 0.f) + rv[j];
    STORE16(hA + (size_t)n * HD + c0, acc);
  }
}

// hBp = dis[n] * (hA @ Wg)
__global__ __launch_bounds__(256) void k_gcnmm(
    const float* __restrict__ hA, const float* __restrict__ Wg,
    const float* __restrict__ dis, float* __restrict__ hBp) {
  int n = blockIdx.x * 256 + threadIdx.x;
  if (n >= NODES) return;
  const float* arow = hA + (size_t)n * HD;
  float di = dis[n];
  for (int cc = 0; cc < 4; cc++) {
    int c0 = cc * 16;
    float acc[16];
#pragma unroll
    for (int j = 0; j < 16; j++) acc[j] = 0.f;
    for (int kc = 0; kc < 4; kc++) {
      float av[16];
      LOAD16(av, arow + kc * 16);
#pragma unroll
      for (int kk = 0; kk < 16; kk++)
#pragma unroll
        for (int j = 0; j < 16; j++)
          acc[j] = fmaf(av[kk], Wg[(kc * 16 + kk) * HD + c0 + j], acc[j]);
    }
#pragma unroll
    for (int j = 0; j < 16; j++) acc[j] *= di;
    STORE16(hBp + (size_t)n * HD + c0, acc);
  }
}

// regressor head: out = relu(relu(hC@W1+b1)@W2+b2)@W3+b3
__global__ __launch_bounds__(256) void k_reg(
    const float* __restrict__ hC,
    const float* __restrict__ W1, const float* __restrict__ b1,
    const float* __restrict__ W2, const float* __restrict__ b2,
    const float* __restrict__ W3, const float* __restrict__ b3,
    float* __restrict__ tmp1, float* __restrict__ tmp2,
    float* __restrict__ out) {
  int n = blockIdx.x * 256 + threadIdx.x;
  if (n >= NODES) return;
  const float* crow = hC + (size_t)n * HD;
  // stage 1: t1 = relu(hC@W1 + b1)  [64]
  for (int cc = 0; cc < 4; cc++) {
    int c0 = cc * 16;
    float acc[16];
#pragma unroll
    for (int j = 0; j < 16; j++) acc[j] = b1[c0 + j];
    for (int kc = 0; kc < 4; kc++) {
      float av[16];
      LOAD16(av, crow + kc * 16);
#pragma unroll
      for (int kk = 0; kk < 16; kk++)
#pragma unroll
        for (int j = 0; j < 16; j++)
          acc[j] = fmaf(av[kk], W1[(kc * 16 + kk) * HD + c0 + j], acc[j]);
    }
#pragma unroll
    for (int j = 0; j < 16; j++) acc[j] = fmaxf(acc[j], 0.f);
    STORE16(tmp1 + (size_t)n * HD + c0, acc);
  }
  // stage 2: t2 = relu(t1@W2 + b2)  [32]
  const float* t1row = tmp1 + (size_t)n * HD;
  for (int cc = 0; cc < 2; cc++) {
    int c0 = cc * 16;
    float acc[16];
#pragma unroll
    for (int j = 0; j < 16; j++) acc[j] = b2[c0 + j];
    for (int kc = 0; kc < 4; kc++) {
      float av[16];
      LOAD16(av, t1row + kc * 16);
#pragma unroll
      for (int kk = 0; kk < 16; kk++)
#pragma unroll
        for (int j = 0; j < 16; j++)
          acc[j] = fmaf(av[kk], W2[(kc * 16 + kk) * 32 + c0 + j], acc[j]);
    }
#pragma unroll
    for (int j = 0; j < 16; j++) acc[j] = fmaxf(acc[j], 0.f);
    STORE16(tmp2 + (size_t)n * 32 + c0, acc);
  }
  // stage 3: out = t2 . W3 + b3
  float t2v[16], t2w[16];
  LOAD16(t2v, tmp2 + (size_t)n * 32);
  LOAD16(t2w, tmp2 + (size_t)n * 32 + 16);
  float s = b3[0];
#pragma unroll
  for (int j = 0; j < 16; j++) s = fmaf(t2v[j], W3[j], s);
#pragma unroll
  for (int j = 0; j < 16; j++) s = fmaf(t2w[j], W3[16 + j], s);
  out[n] = s;
}

// ---------------- wave-per-node aggregations (scalar CSR walk) ----------------

__global__ __launch_bounds__(256) void k_agg_att(
    const float2* __restrict__ sa, const int* __restrict__ rowptr,
    const float* __restrict__ hA, const float* __restrict__ hB,
    const float* __restrict__ g, const float* __restrict__ bt,
    float* __restrict__ hC) {
  int lane = threadIdx.x & 63;
  int node = __builtin_amdgcn_readfirstlane(blockIdx.x * 4 + (threadIdx.x >> 6));
  if (node >= NODES) return;
  int start = rowptr[node], end = rowptr[node + 1];
  float acc0 = 0.f, acc1 = 0.f, acc2 = 0.f, acc3 = 0.f;
  int m = start;
  for (; m + 4 <= end; m += 4) {
    float2 e0 = sa[m], e1 = sa[m + 1], e2 = sa[m + 2], e3 = sa[m + 3];
    acc0 = fmaf(e0.y, hB[__float_as_int(e0.x) * HD + lane], acc0);
    acc1 = fmaf(e1.y, hB[__float_as_int(e1.x) * HD + lane], acc1);
    acc2 = fmaf(e2.y, hB[__float_as_int(e2.x) * HD + lane], acc2);
    acc3 = fmaf(e3.y, hB[__float_as_int(e3.x) * HD + lane], acc3);
  }
  for (; m < end; m++) {
    float2 e0 = sa[m];
    acc0 = fmaf(e0.y, hB[__float_as_int(e0.x) * HD + lane], acc0);
  }
  float acc = (acc0 + acc1) + (acc2 + acc3);
  float v = fmaxf(acc * (g[lane] * BN_INV) + bt[lane], 0.f) + hA[node * HD + lane];
  hC[node * HD + lane] = v;
}

__global__ __launch_bounds__(256) void k_agg_mean(
    const int* __restrict__ esrc, const int* __restrict__ rowptr,
    const float* __restrict__ hC, float* __restrict__ hM) {
  int lane = threadIdx.x & 63;
  int node = __builtin_amdgcn_readfirstlane(blockIdx.x * 4 + (threadIdx.x >> 6));
  if (node >= NODES) return;
  int start = rowptr[node], end = rowptr[node + 1];
  float acc0 = 0.f, acc1 = 0.f, acc2 = 0.f, acc3 = 0.f;
  int m = start;
  for (; m + 4 <= end; m += 4) {
    int s0 = esrc[m], s1 = esrc[m + 1], s2 = esrc[m + 2], s3 = esrc[m + 3];
    acc0 += hC[s0 * HD + lane];
    acc1 += hC[s1 * HD + lane];
    acc2 += hC[s2 * HD + lane];
    acc3 += hC[s3 * HD + lane];
  }
  for (; m < end; m++) acc0 += hC[esrc[m] * HD + lane];
  float acc = (acc0 + acc1) + (acc2 + acc3);
  float degf = (float)(end - start);
  hM[node * HD + lane] = acc / fmaxf(degf, 1.f);
}

__global__ __launch_bounds__(256) void k_agg_gcn(
    const int* __restrict__ esrc, const int* __restrict__ rowptr,
    const float* __restrict__ dis,
    const float* __restrict__ hA, const float* __restrict__ hBp,
    const float* __restrict__ bg,
    const float* __restrict__ g, const float* __restrict__ bt,
    float* __restrict__ hC) {
  int lane = threadIdx.x & 63;
  int node = __builtin_amdgcn_readfirstlane(blockIdx.x * 4 + (threadIdx.x >> 6));
  if (node >= NODES) return;
  int start = rowptr[node], end = rowptr[node + 1];
  float acc0 = hBp[node * HD + lane];  // self-loop: dis_n * hw_n
  float acc1 = 0.f, acc2 = 0.f, acc3 = 0.f;
  int m = start;
  for (; m + 4 <= end; m += 4) {
    int s0 = esrc[m], s1 = esrc[m + 1], s2 = esrc[m + 2], s3 = esrc[m + 3];
    acc0 += hBp[s0 * HD + lane];
    acc1 += hBp[s1 * HD + lane];
    acc2 += hBp[s2 * HD + lane];
    acc3 += hBp[s3 * HD + lane];
  }
  for (; m < end; m++) acc0 += hBp[esrc[m] * HD + lane];
  float acc = (acc0 + acc1) + (acc2 + acc3);
  float v = dis[node] * acc + bg[lane];
  v = fmaxf(v * (g[lane] * BN_INV) + bt[lane], 0.f) + hA[node * HD + lane];
  hC[node * HD + lane] = v;
}

// ---------------- host launch ----------------

extern "C" void kernel_launch(void* const* d_in, const int* in_sizes, int n_in,
                              void* d_out, int out_size, void* d_ws, size_t ws_size,
                              hipStream_t stream) {
  const float* x      = (const float*)d_in[0];
  const float* ea     = (const float*)d_in[1];
  const int*   ei     = (const int*)d_in[2];
  const float* W_node = (const float*)d_in[3];
  const float* b_node = (const float*)d_in[4];
  // d_in[5], d_in[6]: W_edge/b_edge — unused by the reference output
  const float* W_lin0 = (const float*)d_in[7];
  const float* b_lin0 = (const float*)d_in[8];
  const float* W_att0 = (const float*)d_in[9];
  const float* b_att0 = (const float*)d_in[10];
  const float* W_sl   = (const float*)d_in[11];
  const float* b_sl   = (const float*)d_in[12];
  const float* W_sr   = (const float*)d_in[13];
  const float* W_gcn  = (const float*)d_in[14];
  const float* b_gcn  = (const float*)d_in[15];
  const float* bn_g   = (const float*)d_in[16];  // [3,64]
  const float* bn_b   = (const float*)d_in[17];
  const float* W_r1   = (const float*)d_in[18];
  const float* b_r1   = (const float*)d_in[19];
  const float* W_r2   = (const float*)d_in[20];
  const float* b_r2   = (const float*)d_in[21];
  const float* W_r3   = (const float*)d_in[22];
  const float* b_r3   = (const float*)d_in[23];
  float* out = (float*)d_out;

  char* ws = (char*)d_ws;
  size_t o = 0;
  auto alloc = [&](size_t bytes) -> void* {
    void* p = ws + o;
    o += (bytes + 255) & ~(size_t)255;
    return p;
  };
  int*    deg    = (int*)alloc(NODES * 4);
  int*    rowptr = (int*)alloc((NODES + 1) * 4);
  int*    cur    = (int*)alloc(NODES * 4);
  int*    part   = (int*)alloc(256 * 4);
  float4* edat   = (float4*)alloc((size_t)EDGES * 16);
  int*    esrc   = (int*)alloc((size_t)EDGES * 4);
  float2* sa     = (float2*)alloc((size_t)EDGES * 8);
  float*  hA     = (float*)alloc((size_t)NODES * HD * 4);
  float*  hB     = (float*)alloc((size_t)NODES * HD * 4);
  float*  hC     = (float*)alloc((size_t)NODES * HD * 4);
  float*  cvec   = (float*)alloc(NODES * 4);
  float*  dvec   = (float*)alloc(NODES * 4);
  float*  dis    = (float*)alloc(NODES * 4);
  (void)ws_size; (void)in_sizes; (void)n_in; (void)out_size;

  const int EB  = (EDGES + 255) / 256;
  const int NB  = (NODES + 255) / 256;   // thread-per-node
  const int NBW = (NODES + 3) / 4;       // wave-per-node (4 waves/block)

  k_zero<<<(NODES + 255) / 256, 256, 0, stream>>>(deg, NODES);
  k_hist<<<EB, 256, 0, stream>>>(ei, deg);
  k_scan1<<<NCHUNK, 256, 0, stream>>>(deg, part);
  k_scan2<<<1, 64, 0, stream>>>(part);
  k_scan3<<<NCHUNK, 256, 0, stream>>>(deg, part, rowptr, cur, dis);
  k_fill<<<EB, 256, 0, stream>>>(ei, ea, cur, esrc, edat);

  k_lin0<<<NB, 256, 0, stream>>>(x, W_node, b_node, W_lin0, b_lin0, W_att0,
                                 hA, hB, cvec, dvec);
  k_att<<<EB, 256, 0, stream>>>(esrc, edat, cvec, dvec, W_att0, b_att0, sa);
  k_agg_att<<<NBW, 256, 0, stream>>>(sa, rowptr, hA, hB,
                                     bn_g + 0 * HD, bn_b + 0 * HD, hC);
  // hB now dead -> reuse as mean buffer
  k_agg_mean<<<NBW, 256, 0, stream>>>(esrc, rowptr, hC, hB);
  k_sage<<<NB, 256, 0, stream>>>(hB, hC, W_sl, b_sl, W_sr,
                                 bn_g + 1 * HD, bn_b + 1 * HD, hA);
  k_gcnmm<<<NB, 256, 0, stream>>>(hA, W_gcn, dis, hB);
  k_agg_gcn<<<NBW, 256, 0, stream>>>(esrc, rowptr, dis, hA, hB, b_gcn,
                                     bn_g + 2 * HD, bn_b + 2 * HD, hC);
  // hA, hB dead -> reuse as regressor temporaries
  k_reg<<<NB, 256, 0, stream>>>(hC, W_r1, b_r1, W_r2, b_r2, W_r3, b_r3,
                                hA, hB, out);
}

// Round 3
// 469.355 us; speedup vs baseline: 2.0369x; 1.0429x over previous
//
#include <hip/hip_runtime.h>
#include <math.h>

#define NODES 100000
#define EDGES 1250000
#define HD 64
#define NFD 16
#define CHUNK 1024
#define NCHUNK ((NODES + CHUNK - 1) / CHUNK)
#define BN_INV 0.9999950000374996f  // 1/sqrt(1+1e-5)

#define LOAD16(dst, ptr)                                   \
  {                                                        \
    const float4* _p = (const float4*)(ptr);               \
    float4 _a = _p[0], _b = _p[1], _c = _p[2], _d = _p[3]; \
    dst[0] = _a.x; dst[1] = _a.y; dst[2] = _a.z; dst[3] = _a.w;    \
    dst[4] = _b.x; dst[5] = _b.y; dst[6] = _b.z; dst[7] = _b.w;    \
    dst[8] = _c.x; dst[9] = _c.y; dst[10] = _c.z; dst[11] = _c.w;  \
    dst[12] = _d.x; dst[13] = _d.y; dst[14] = _d.z; dst[15] = _d.w; \
  }

#define STORE16(ptr, src)                                       \
  {                                                             \
    float4* _p = (float4*)(ptr);                                \
    _p[0] = make_float4(src[0], src[1], src[2], src[3]);        \
    _p[1] = make_float4(src[4], src[5], src[6], src[7]);        \
    _p[2] = make_float4(src[8], src[9], src[10], src[11]);      \
    _p[3] = make_float4(src[12], src[13], src[14], src[15]);    \
  }

// ---------------- graph build ----------------

__global__ void k_zero(int* __restrict__ p, int n) {
  int i = blockIdx.x * blockDim.x + threadIdx.x;
  if (i < n) p[i] = 0;
}

__global__ void k_hist(const int* __restrict__ ei, int* __restrict__ deg) {
  int e = blockIdx.x * blockDim.x + threadIdx.x;
  if (e < EDGES) atomicAdd(&deg[ei[EDGES + e]], 1);
}

__global__ void k_scan1(const int* __restrict__ deg, int* __restrict__ part) {
  __shared__ int lds[256];
  int t = threadIdx.x, b = blockIdx.x;
  int base = b * CHUNK + t * 4;
  int s = 0;
#pragma unroll
  for (int m = 0; m < 4; m++) { int i = base + m; if (i < NODES) s += deg[i]; }
  lds[t] = s; __syncthreads();
  for (int off = 128; off > 0; off >>= 1) {
    if (t < off) lds[t] += lds[t + off];
    __syncthreads();
  }
  if (t == 0) part[b] = lds[0];
}

__global__ void k_scan2(int* __restrict__ part) {
  if (threadIdx.x == 0 && blockIdx.x == 0) {
    int run = 0;
    for (int c = 0; c < NCHUNK; c++) { int v = part[c]; part[c] = run; run += v; }
  }
}

__global__ void k_scan3(const int* __restrict__ deg, const int* __restrict__ part,
                        int* __restrict__ rowptr, int* __restrict__ cur,
                        float* __restrict__ dis) {
  __shared__ int lds[256];
  int t = threadIdx.x, b = blockIdx.x;
  int base = b * CHUNK + t * 4;
  int dl[4]; int s = 0;
#pragma unroll
  for (int m = 0; m < 4; m++) { int i = base + m; dl[m] = (i < NODES) ? deg[i] : 0; s += dl[m]; }
  lds[t] = s; __syncthreads();
  for (int off = 1; off < 256; off <<= 1) {
    int add = (t >= off) ? lds[t - off] : 0;
    __syncthreads();
    lds[t] += add;
    __syncthreads();
  }
  int run = part[b] + lds[t] - s;  // exclusive prefix for this thread
#pragma unroll
  for (int m = 0; m < 4; m++) {
    int i = base + m;
    if (i < NODES) {
      rowptr[i] = run; cur[i] = run;
      dis[i] = 1.0f / sqrtf((float)(dl[m] + 1));  // GCN: indeg + self-loop
    }
    run += dl[m];
  }
  if (b == 0 && t == 0) rowptr[NODES] = EDGES;
}

// attention coeff in ORIGINAL edge order, then single 8B scattered write
__global__ void k_fillatt(const int* __restrict__ ei, const float* __restrict__ ea,
                          const float* __restrict__ cvec, const float* __restrict__ dvec,
                          const float* __restrict__ Wa, const float* __restrict__ ba,
                          int* __restrict__ cur, float2* __restrict__ sa) {
  int e = blockIdx.x * blockDim.x + threadIdx.x;
  if (e >= EDGES) return;
  int s = ei[e], d = ei[EDGES + e];
  float alin = cvec[d] + dvec[s] + ea[3 * e] * Wa[128] + ea[3 * e + 1] * Wa[129] +
               ea[3 * e + 2] * Wa[130] + ba[0];
  float lr = alin >= 0.f ? alin : 0.01f * alin;
  float a = 1.f / (1.f + expf(-lr));
  int p = atomicAdd(&cur[d], 1);
  sa[p] = make_float2(__int_as_float(s), a);
}

// ---------------- row-per-thread node GEMMs ----------------

// h = x@Wn + bn -> hA ; h0 = h@Wl + bl -> hB ; cvec = h0.Wa[0:64] ; dvec = h0.Wa[64:128]
__global__ __launch_bounds__(256) void k_lin0(
    const float* __restrict__ x,
    const float* __restrict__ Wn, const float* __restrict__ bn,
    const float* __restrict__ Wl, const float* __restrict__ bl,
    const float* __restrict__ Wa,
    float* __restrict__ hA, float* __restrict__ hB,
    float* __restrict__ cvec, float* __restrict__ dvec) {
  int n = blockIdx.x * 256 + threadIdx.x;
  if (n >= NODES) return;
  float xv[16];
  LOAD16(xv, x + (size_t)n * NFD);
  float hv[64];
  // stage 1: h = x@Wn + bn  (kept in regs, also stored as ident)
  for (int cc = 0; cc < 4; cc++) {
    int c0 = cc * 16;
    float acc[16];
#pragma unroll
    for (int j = 0; j < 16; j++) acc[j] = bn[c0 + j];
#pragma unroll
    for (int k = 0; k < 16; k++)
#pragma unroll
      for (int j = 0; j < 16; j++)
        acc[j] = fmaf(xv[k], Wn[k * HD + c0 + j], acc[j]);
#pragma unroll
    for (int j = 0; j < 16; j++) hv[c0 + j] = acc[j];
    STORE16(hA + (size_t)n * HD + c0, acc);
  }
  // stage 2: h0 = h@Wl + bl (+ attention dot precompute)
  float cn = 0.f, dn = 0.f;
  for (int cc = 0; cc < 4; cc++) {
    int c0 = cc * 16;
    float acc[16];
#pragma unroll
    for (int j = 0; j < 16; j++) acc[j] = bl[c0 + j];
#pragma unroll
    for (int k = 0; k < 64; k++)
#pragma unroll
      for (int j = 0; j < 16; j++)
        acc[j] = fmaf(hv[k], Wl[k * HD + c0 + j], acc[j]);
#pragma unroll
    for (int j = 0; j < 16; j++) {
      cn = fmaf(acc[j], Wa[c0 + j], cn);
      dn = fmaf(acc[j], Wa[64 + c0 + j], dn);
    }
    STORE16(hB + (size_t)n * HD + c0, acc);
  }
  cvec[n] = cn;
  dvec[n] = dn;
}

// fused SAGE epilogue + GCN pre-GEMM:
// t = relu(BN1(mean@Wl + bl + hC@Wr)) + hC -> hA ; hBp = dis * (t@Wg) -> out2
__global__ __launch_bounds__(256) void k_sagegcn(
    const float* __restrict__ hM, const float* __restrict__ hC,
    const float* __restrict__ Wl, const float* __restrict__ bl,
    const float* __restrict__ Wr, const float* __restrict__ Wg,
    const float* __restrict__ g, const float* __restrict__ bt,
    const float* __restrict__ dis,
    float* __restrict__ hA, float* __restrict__ hBp) {
  int n = blockIdx.x * 256 + threadIdx.x;
  if (n >= NODES) return;
  const float* mrow = hM + (size_t)n * HD;
  const float* crow = hC + (size_t)n * HD;
  float t[64];
  for (int cc = 0; cc < 4; cc++) {
    int c0 = cc * 16;
    float acc[16];
#pragma unroll
    for (int j = 0; j < 16; j++) acc[j] = bl[c0 + j];
    for (int kc = 0; kc < 4; kc++) {
      float av[16], bv[16];
      LOAD16(av, mrow + kc * 16);
      LOAD16(bv, crow + kc * 16);
#pragma unroll
      for (int kk = 0; kk < 16; kk++)
#pragma unroll
        for (int j = 0; j < 16; j++)
          acc[j] = fmaf(av[kk], Wl[(kc * 16 + kk) * HD + c0 + j], acc[j]);
#pragma unroll
      for (int kk = 0; kk < 16; kk++)
#pragma unroll
        for (int j = 0; j < 16; j++)
          acc[j] = fmaf(bv[kk], Wr[(kc * 16 + kk) * HD + c0 + j], acc[j]);
    }
    float rv[16];
    LOAD16(rv, crow + c0);
#pragma unroll
    for (int j = 0; j < 16; j++)
      t[c0 + j] = fmaxf(acc[j] * (g[c0 + j] * BN_INV) + bt[c0 + j], 0.f) + rv[j];
  }
  for (int cc = 0; cc < 4; cc++) {
    int c0 = cc * 16;
    float st[16];
#pragma unroll
    for (int j = 0; j < 16; j++) st[j] = t[c0 + j];
    STORE16(hA + (size_t)n * HD + c0, st);
  }
  float di = dis[n];
  for (int cc = 0; cc < 4; cc++) {
    int c0 = cc * 16;
    float acc[16];
#pragma unroll
    for (int j = 0; j < 16; j++) acc[j] = 0.f;
#pragma unroll
    for (int k = 0; k < 64; k++)
#pragma unroll
      for (int j = 0; j < 16; j++)
        acc[j] = fmaf(t[k], Wg[k * HD + c0 + j], acc[j]);
#pragma unroll
    for (int j = 0; j < 16; j++) acc[j] *= di;
    STORE16(hBp + (size_t)n * HD + c0, acc);
  }
}

// regressor head, all intermediates in registers
__global__ __launch_bounds__(256) void k_reg(
    const float* __restrict__ hC,
    const float* __restrict__ W1, const float* __restrict__ b1,
    const float* __restrict__ W2, const float* __restrict__ b2,
    const float* __restrict__ W3, const float* __restrict__ b3,
    float* __restrict__ out) {
  int n = blockIdx.x * 256 + threadIdx.x;
  if (n >= NODES) return;
  const float* crow = hC + (size_t)n * HD;
  float cv[64];
  for (int kc = 0; kc < 4; kc++) {
    float av[16];
    LOAD16(av, crow + kc * 16);
#pragma unroll
    for (int j = 0; j < 16; j++) cv[kc * 16 + j] = av[j];
  }
  float t1[64];
  for (int cc = 0; cc < 4; cc++) {
    int c0 = cc * 16;
    float acc[16];
#pragma unroll
    for (int j = 0; j < 16; j++) acc[j] = b1[c0 + j];
#pragma unroll
    for (int k = 0; k < 64; k++)
#pragma unroll
      for (int j = 0; j < 16; j++)
        acc[j] = fmaf(cv[k], W1[k * HD + c0 + j], acc[j]);
#pragma unroll
    for (int j = 0; j < 16; j++) t1[c0 + j] = fmaxf(acc[j], 0.f);
  }
  float t2[32];
  for (int cc = 0; cc < 2; cc++) {
    int c0 = cc * 16;
    float acc[16];
#pragma unroll
    for (int j = 0; j < 16; j++) acc[j] = b2[c0 + j];
#pragma unroll
    for (int k = 0; k < 64; k++)
#pragma unroll
      for (int j = 0; j < 16; j++)
        acc[j] = fmaf(t1[k], W2[k * 32 + c0 + j], acc[j]);
#pragma unroll
    for (int j = 0; j < 16; j++) t2[c0 + j] = fmaxf(acc[j], 0.f);
  }
  float s = b3[0];
#pragma unroll
  for (int j = 0; j < 32; j++) s = fmaf(t2[j], W3[j], s);
  out[n] = s;
}

// ---------------- wave-per-node aggregations (float4 gathers, 4 rows/instr) ----------------

__global__ __launch_bounds__(256) void k_agg_att(
    const float2* __restrict__ sa, const int* __restrict__ rowptr,
    const float* __restrict__ hA, const float* __restrict__ hB,
    const float* __restrict__ g, const float* __restrict__ bt,
    float* __restrict__ hC) {
  int lane = threadIdx.x & 63;
  int node = __builtin_amdgcn_readfirstlane(blockIdx.x * 4 + (threadIdx.x >> 6));
  if (node >= NODES) return;
  int start = rowptr[node], end = rowptr[node + 1];
  int sub = lane >> 4;  // edge slot 0..3
  int col = lane & 15;  // float4 column group
  float4 acc0 = make_float4(0.f, 0.f, 0.f, 0.f);
  float4 acc1 = make_float4(0.f, 0.f, 0.f, 0.f);
  int last = end - 1;
  for (int m = start; m < end; m += 8) {
    int e0 = m + sub, e1 = m + sub + 4;
    float2 s0 = sa[min(e0, last)], s1 = sa[min(e1, last)];
    float w0 = (e0 < end) ? s0.y : 0.f;
    float w1 = (e1 < end) ? s1.y : 0.f;
    float4 v0 = *((const float4*)(hB + (size_t)__float_as_int(s0.x) * HD) + col);
    float4 v1 = *((const float4*)(hB + (size_t)__float_as_int(s1.x) * HD) + col);
    acc0.x = fmaf(w0, v0.x, acc0.x); acc0.y = fmaf(w0, v0.y, acc0.y);
    acc0.z = fmaf(w0, v0.z, acc0.z); acc0.w = fmaf(w0, v0.w, acc0.w);
    acc1.x = fmaf(w1, v1.x, acc1.x); acc1.y = fmaf(w1, v1.y, acc1.y);
    acc1.z = fmaf(w1, v1.z, acc1.z); acc1.w = fmaf(w1, v1.w, acc1.w);
  }
  acc0.x += acc1.x; acc0.y += acc1.y; acc0.z += acc1.z; acc0.w += acc1.w;
#pragma unroll
  for (int off = 16; off <= 32; off <<= 1) {
    acc0.x += __shfl_xor(acc0.x, off); acc0.y += __shfl_xor(acc0.y, off);
    acc0.z += __shfl_xor(acc0.z, off); acc0.w += __shfl_xor(acc0.w, off);
  }
  if (lane < 16) {
    float4 gg = ((const float4*)g)[lane];
    float4 bb = ((const float4*)bt)[lane];
    float4 ha = *((const float4*)(hA + (size_t)node * HD) + lane);
    float4 v;
    v.x = fmaxf(acc0.x * (gg.x * BN_INV) + bb.x, 0.f) + ha.x;
    v.y = fmaxf(acc0.y * (gg.y * BN_INV) + bb.y, 0.f) + ha.y;
    v.z = fmaxf(acc0.z * (gg.z * BN_INV) + bb.z, 0.f) + ha.z;
    v.w = fmaxf(acc0.w * (gg.w * BN_INV) + bb.w, 0.f) + ha.w;
    *((float4*)(hC + (size_t)node * HD) + lane) = v;
  }
}

__global__ __launch_bounds__(256) void k_agg_mean(
    const float2* __restrict__ sa, const int* __restrict__ rowptr,
    const float* __restrict__ hC, float* __restrict__ hM) {
  int lane = threadIdx.x & 63;
  int node = __builtin_amdgcn_readfirstlane(blockIdx.x * 4 + (threadIdx.x >> 6));
  if (node >= NODES) return;
  int start = rowptr[node], end = rowptr[node + 1];
  int sub = lane >> 4;
  int col = lane & 15;
  float4 acc0 = make_float4(0.f, 0.f, 0.f, 0.f);
  float4 acc1 = make_float4(0.f, 0.f, 0.f, 0.f);
  int last = end - 1;
  for (int m = start; m < end; m += 8) {
    int e0 = m + sub, e1 = m + sub + 4;
    float2 s0 = sa[min(e0, last)], s1 = sa[min(e1, last)];
    float w0 = (e0 < end) ? 1.f : 0.f;
    float w1 = (e1 < end) ? 1.f : 0.f;
    float4 v0 = *((const float4*)(hC + (size_t)__float_as_int(s0.x) * HD) + col);
    float4 v1 = *((const float4*)(hC + (size_t)__float_as_int(s1.x) * HD) + col);
    acc0.x = fmaf(w0, v0.x, acc0.x); acc0.y = fmaf(w0, v0.y, acc0.y);
    acc0.z = fmaf(w0, v0.z, acc0.z); acc0.w = fmaf(w0, v0.w, acc0.w);
    acc1.x = fmaf(w1, v1.x, acc1.x); acc1.y = fmaf(w1, v1.y, acc1.y);
    acc1.z = fmaf(w1, v1.z, acc1.z); acc1.w = fmaf(w1, v1.w, acc1.w);
  }
  acc0.x += acc1.x; acc0.y += acc1.y; acc0.z += acc1.z; acc0.w += acc1.w;
#pragma unroll
  for (int off = 16; off <= 32; off <<= 1) {
    acc0.x += __shfl_xor(acc0.x, off); acc0.y += __shfl_xor(acc0.y, off);
    acc0.z += __shfl_xor(acc0.z, off); acc0.w += __shfl_xor(acc0.w, off);
  }
  if (lane < 16) {
    float rdeg = 1.f / fmaxf((float)(end - start), 1.f);
    float4 v;
    v.x = acc0.x * rdeg; v.y = acc0.y * rdeg; v.z = acc0.z * rdeg; v.w = acc0.w * rdeg;
    *((float4*)(hM + (size_t)node * HD) + lane) = v;
  }
}

__global__ __launch_bounds__(256) void k_agg_gcn(
    const float2* __restrict__ sa, const int* __restrict__ rowptr,
    const float* __restrict__ dis,
    const float* __restrict__ hA, const float* __restrict__ hBp,
    const float* __restrict__ bg,
    const float* __restrict__ g, const float* __restrict__ bt,
    float* __restrict__ hC) {
  int lane = threadIdx.x & 63;
  int node = __builtin_amdgcn_readfirstlane(blockIdx.x * 4 + (threadIdx.x >> 6));
  if (node >= NODES) return;
  int start = rowptr[node], end = rowptr[node + 1];
  int sub = lane >> 4;
  int col = lane & 15;
  float4 acc0 = make_float4(0.f, 0.f, 0.f, 0.f);
  float4 acc1 = make_float4(0.f, 0.f, 0.f, 0.f);
  int last = end - 1;
  for (int m = start; m < end; m += 8) {
    int e0 = m + sub, e1 = m + sub + 4;
    float2 s0 = sa[min(e0, last)], s1 = sa[min(e1, last)];
    float w0 = (e0 < end) ? 1.f : 0.f;
    float w1 = (e1 < end) ? 1.f : 0.f;
    float4 v0 = *((const float4*)(hBp + (size_t)__float_as_int(s0.x) * HD) + col);
    float4 v1 = *((const float4*)(hBp + (size_t)__float_as_int(s1.x) * HD) + col);
    acc0.x = fmaf(w0, v0.x, acc0.x); acc0.y = fmaf(w0, v0.y, acc0.y);
    acc0.z = fmaf(w0, v0.z, acc0.z); acc0.w = fmaf(w0, v0.w, acc0.w);
    acc1.x = fmaf(w1, v1.x, acc1.x); acc1.y = fmaf(w1, v1.y, acc1.y);
    acc1.z = fmaf(w1, v1.z, acc1.z); acc1.w = fmaf(w1, v1.w, acc1.w);
  }
  acc0.x += acc1.x; acc0.y += acc1.y; acc0.z += acc1.z; acc0.w += acc1.w;
#pragma unroll
  for (int off = 16; off <= 32; off <<= 1) {
    acc0.x += __shfl_xor(acc0.x, off); acc0.y += __shfl_xor(acc0.y, off);
    acc0.z += __shfl_xor(acc0.z, off); acc0.w += __shfl_xor(acc0.w, off);
  }
  if (lane < 16) {
    float4 sv = *((const float4*)(hBp + (size_t)node * HD) + lane);  // self-loop
    float di = dis[node];
    float4 gg = ((const float4*)g)[lane];
    float4 bb = ((const float4*)bt)[lane];
    float4 ha = *((const float4*)(hA + (size_t)node * HD) + lane);
    float4 bgv = ((const float4*)bg)[lane];
    float4 v;
    v.x = fmaxf((di * (acc0.x + sv.x) + bgv.x) * (gg.x * BN_INV) + bb.x, 0.f) + ha.x;
    v.y = fmaxf((di * (acc0.y + sv.y) + bgv.y) * (gg.y * BN_INV) + bb.y, 0.f) + ha.y;
    v.z = fmaxf((di * (acc0.z + sv.z) + bgv.z) * (gg.z * BN_INV) + bb.z, 0.f) + ha.z;
    v.w = fmaxf((di * (acc0.w + sv.w) + bgv.w) * (gg.w * BN_INV) + bb.w, 0.f) + ha.w;
    *((float4*)(hC + (size_t)node * HD) + lane) = v;
  }
}

// ---------------- host launch ----------------

extern "C" void kernel_launch(void* const* d_in, const int* in_sizes, int n_in,
                              void* d_out, int out_size, void* d_ws, size_t ws_size,
                              hipStream_t stream) {
  const float* x      = (const float*)d_in[0];
  const float* ea     = (const float*)d_in[1];
  const int*   ei     = (const int*)d_in[2];
  const float* W_node = (const float*)d_in[3];
  const float* b_node = (const float*)d_in[4];
  // d_in[5], d_in[6]: W_edge/b_edge — unused by the reference output
  const float* W_lin0 = (const float*)d_in[7];
  const float* b_lin0 = (const float*)d_in[8];
  const float* W_att0 = (const float*)d_in[9];
  const float* b_att0 = (const float*)d_in[10];
  const float* W_sl   = (const float*)d_in[11];
  const float* b_sl   = (const float*)d_in[12];
  const float* W_sr   = (const float*)d_in[13];
  const float* W_gcn  = (const float*)d_in[14];
  const float* b_gcn  = (const float*)d_in[15];
  const float* bn_g   = (const float*)d_in[16];  // [3,64]
  const float* bn_b   = (const float*)d_in[17];
  const float* W_r1   = (const float*)d_in[18];
  const float* b_r1   = (const float*)d_in[19];
  const float* W_r2   = (const float*)d_in[20];
  const float* b_r2   = (const float*)d_in[21];
  const float* W_r3   = (const float*)d_in[22];
  const float* b_r3   = (const float*)d_in[23];
  float* out = (float*)d_out;

  char* ws = (char*)d_ws;
  size_t o = 0;
  auto alloc = [&](size_t bytes) -> void* {
    void* p = ws + o;
    o += (bytes + 255) & ~(size_t)255;
    return p;
  };
  int*    deg    = (int*)alloc(NODES * 4);
  int*    rowptr = (int*)alloc((NODES + 1) * 4);
  int*    cur    = (int*)alloc(NODES * 4);
  int*    part   = (int*)alloc(256 * 4);
  float2* sa     = (float2*)alloc((size_t)EDGES * 8);
  float*  hA     = (float*)alloc((size_t)NODES * HD * 4);
  float*  hB     = (float*)alloc((size_t)NODES * HD * 4);
  float*  hC     = (float*)alloc((size_t)NODES * HD * 4);
  float*  cvec   = (float*)alloc(NODES * 4);
  float*  dvec   = (float*)alloc(NODES * 4);
  float*  dis    = (float*)alloc(NODES * 4);
  (void)ws_size; (void)in_sizes; (void)n_in; (void)out_size;

  const int EB  = (EDGES + 255) / 256;
  const int NB  = (NODES + 255) / 256;   // thread-per-node
  const int NBW = (NODES + 3) / 4;       // wave-per-node (4 waves/block)

  k_zero<<<(NODES + 255) / 256, 256, 0, stream>>>(deg, NODES);
  k_hist<<<EB, 256, 0, stream>>>(ei, deg);
  k_scan1<<<NCHUNK, 256, 0, stream>>>(deg, part);
  k_scan2<<<1, 64, 0, stream>>>(part);
  k_scan3<<<NCHUNK, 256, 0, stream>>>(deg, part, rowptr, cur, dis);

  k_lin0<<<NB, 256, 0, stream>>>(x, W_node, b_node, W_lin0, b_lin0, W_att0,
                                 hA, hB, cvec, dvec);
  k_fillatt<<<EB, 256, 0, stream>>>(ei, ea, cvec, dvec, W_att0, b_att0, cur, sa);
  k_agg_att<<<NBW, 256, 0, stream>>>(sa, rowptr, hA, hB,
                                     bn_g + 0 * HD, bn_b + 0 * HD, hC);
  // hB dead -> reuse as mean buffer
  k_agg_mean<<<NBW, 256, 0, stream>>>(sa, rowptr, hC, hB);
  // fused SAGE + GCN pre-GEMM: writes t -> hA, dis*(t@Wg) -> hB
  k_sagegcn<<<NB, 256, 0, stream>>>(hB, hC, W_sl, b_sl, W_sr, W_gcn,
                                    bn_g + 1 * HD, bn_b + 1 * HD, dis, hA, hB);
  k_agg_gcn<<<NBW, 256, 0, stream>>>(sa, rowptr, dis, hA, hB, b_gcn,
                                     bn_g + 2 * HD, bn_b + 2 * HD, hC);
  k_reg<<<NB, 256, 0, stream>>>(hC, W_r1, b_r1, W_r2, b_r2, W_r3, b_r3, out);
}